// Round 1
// baseline (138.541 us; speedup 1.0000x reference)
//
#include <hip/hip_runtime.h>
#include <hip/hip_bf16.h>
#include <hip/hip_fp8.h>

typedef __attribute__((ext_vector_type(4))) int i32x4;
typedef __attribute__((ext_vector_type(8))) int i32x8;
typedef __attribute__((ext_vector_type(16))) float f32x16;

#define MARGIN 0.3f
#define BIGF 3.0e38f

__device__ __forceinline__ void gl2lds16(const void* g, void* l) {
    __builtin_amdgcn_global_load_lds(
        (const __attribute__((address_space(1))) void*)g,
        (__attribute__((address_space(3))) void*)l,
        16, 0, 0);
}

// Wave-per-row convert: fp32 -> fp8 e4m3 (OCP) cast, fp32 row norm of the
// fp8-ROUNDED values (consistent with MFMA dots -> exact diagonal), init
// ap/an/cnt. 4 rows per 256-thread block. (R7/R8/R11-verified; UNCHANGED.)
__global__ __launch_bounds__(256) void convert_norm_kernel(
    const float* __restrict__ X, unsigned char* __restrict__ Xq,
    float* __restrict__ nrm, unsigned* __restrict__ ap,
    unsigned* __restrict__ an, unsigned* __restrict__ cnt, int K) {
    const int wave = threadIdx.x >> 6, lane = threadIdx.x & 63;
    const int row = blockIdx.x * 4 + wave;
    const float* xr = X + (size_t)row * K;
    unsigned char* xqr = Xq + (size_t)row * K;
    float s = 0.0f;
    for (int c = lane * 8; c < K; c += 64 * 8) {
        float4 v0 = *(const float4*)(xr + c);
        float4 v1 = *(const float4*)(xr + c + 4);
        float f[8] = {v0.x, v0.y, v0.z, v0.w, v1.x, v1.y, v1.z, v1.w};
        union { unsigned char b[8]; uint2 u; } p;
#pragma unroll
        for (int i = 0; i < 8; i++) {
            __hip_fp8_e4m3 q(f[i]);       // OCP e4m3, RNE+saturate
            p.b[i] = q.__x;
            float d = (float)q;           // decoded value
            s += d * d;
        }
        *(uint2*)(xqr + c) = p.u;
    }
    for (int off = 32; off > 0; off >>= 1) s += __shfl_xor(s, off, 64);
    if (lane == 0) {
        nrm[row] = s;
        ap[row] = 0u;           // dist_ap >= 0 always (self is a positive)
        an[row] = 0x7F800000u;  // +inf
        if (row == 0) *cnt = 0u;
    }
}

// 256x256-tile fp8-MX GEMM-reduce, 8 waves (2x4), wave tile 128x64 = 4x2
// subtiles of 32x32x64 mfma_scale (unit scales 0x7F). Grid = 16x16 = 256
// blocks = exactly 1/CU (no tail). vs the previous 128^2 kernel:
//  - LDS bytes/MFMA 32 -> 24 B (A frags reused 2x, B frags 4x): per-CU
//    per-K-iter MFMA work 2200 cy > LDS 1540 cy -> LDS off critical path.
//  - Double-buffered LDS (2 x (32KB A + 32KB B) = 128 KB): next tile's
//    gl2lds issued at phase start, drained ONLY at the iter boundary
//    (__syncthreads); phase boundaries use RAW s_barrier so the prefetch
//    stays in flight across them (T3/T4 minimum 2-phase form).
//  - s_setprio(1) around each 8-MFMA cluster (T5).
//  - Swizzle upgraded BOTH sides: phys_chunk = logical ^ (row&7) ^
//    ((row>>3)&3). Staging source chunk gets the extra ^g (g = 8-row group
//    index = (row>>3)&3 since wave regions are 32-aligned); read unswizzle
//    key e2 = (m&7) ^ ((m>>3)&3). Kills the 8-lanes-per-chunk-column
//    pattern behind the 4.19M SQ_LDS_BANK_CONFLICT cycles.
// Carried-over verified pieces: staging lane math (dest = uniform base +
// lane*16 -> row l>>3, phys chunk l&7), operand layout (lane m = row,
// h = k-half), C/D map col=lane&31 row=(reg&3)+8*(reg>>2)+4*(lane>>5),
// monotone uint atomics, fused last-block loss.
__global__ __launch_bounds__(512, 2) void gemm_reduce_kernel(
    const unsigned char* __restrict__ Xq, const float* __restrict__ nrm,
    const int* __restrict__ Y, unsigned* __restrict__ ap,
    unsigned* __restrict__ an, unsigned* __restrict__ cnt,
    float* __restrict__ out, int N, int K) {
    __shared__ __align__(16) unsigned char sA[2][32768];  // 64 KB
    __shared__ __align__(16) unsigned char sB[2][32768];  // 64 KB
    __shared__ int sYr[256], sYc[256];
    __shared__ float sNr[256], sNc[256];
    __shared__ float redmax[4][256], redmin[4][256];      // [wc][row]
    __shared__ float lsum[8];
    __shared__ unsigned s_done;

    const int tid = threadIdx.x;
    const int wave = tid >> 6;
    const int lane = tid & 63;
    const int m = lane & 31;   // row within 32x32 subtile / col within subtile
    const int h = lane >> 5;   // k-half (inputs) / row-group (outputs)
    const int wr = wave >> 2;  // wave row (0..1): rows wr*128..+127
    const int wc = wave & 3;   // wave col (0..3): cols wc*64..+63

    const int NB = N >> 8;  // 16
    const int rowBase = (blockIdx.x / NB) << 8;
    const int colBase = (blockIdx.x % NB) << 8;

    if (tid < 256) {
        sYr[tid] = Y[rowBase + tid];
        sNr[tid] = nrm[rowBase + tid];
    } else {
        const int t = tid - 256;
        sYc[t] = Y[colBase + t];
        sNc[t] = nrm[colBase + t];
    }

    f32x16 acc[4][2];
#pragma unroll
    for (int si = 0; si < 4; si++)
#pragma unroll
        for (int sj = 0; sj < 2; sj++)
#pragma unroll
            for (int rr = 0; rr < 16; rr++) acc[si][sj][rr] = 0.0f;

    // Staging: each wave stages its 32 rows of A and of B per K-tile
    // (4 gl2lds each, 1 KB per gl2lds). Lane l -> LDS row (l>>3) of the
    // 8-row group g, phys chunk l&7; source logical chunk = (l&7)^(l>>3)^g
    // so phys = logical ^ (row&7) ^ ((row>>3)&3).
    const int rsub = lane >> 3;
    const int jc = (lane & 7) ^ rsub;
    const unsigned char* gA = Xq + (size_t)(rowBase + wave * 32 + rsub) * K;
    const unsigned char* gB = Xq + (size_t)(colBase + wave * 32 + rsub) * K;
    const size_t g8 = (size_t)8 * K;  // 8 rows, bytes

    const int e2 = (m & 7) ^ ((m >> 3) & 3);  // read-side unswizzle key
    const int nit = K >> 7;                   // BK=128 bytes (16 iters)

    // Prologue: stage tile 0 into buffer 0, drain, full barrier.
#pragma unroll
    for (int g = 0; g < 4; g++) {
        gl2lds16(gA + g * g8 + ((jc ^ g) << 4), &sA[0][wave * 4096 + g * 1024]);
        gl2lds16(gB + g * g8 + ((jc ^ g) << 4), &sB[0][wave * 4096 + g * 1024]);
    }
    __syncthreads();  // drains vmcnt for gl2lds

    int cur = 0;
    for (int it = 0; it < nit; ++it) {
        const bool pf = (it + 1 < nit);  // block-uniform
        const size_t go = (size_t)(it + 1) * 128;
        const unsigned char* cA = sA[cur];
        const unsigned char* cB = sB[cur];
        unsigned char* nA = sA[cur ^ 1] + wave * 4096;
        unsigned char* nB = sB[cur ^ 1] + wave * 4096;

#pragma unroll
        for (int s = 0; s < 2; s++) {  // two k64 phases per BK=128
            // Issue half the next-tile prefetch this phase (stays in
            // flight across the raw barriers below).
            if (pf) {
                if (s == 0) {
#pragma unroll
                    for (int g = 0; g < 4; g++)
                        gl2lds16(gA + go + g * g8 + ((jc ^ g) << 4), nA + g * 1024);
                } else {
#pragma unroll
                    for (int g = 0; g < 4; g++)
                        gl2lds16(gB + go + g * g8 + ((jc ^ g) << 4), nB + g * 1024);
                }
            }
            const int c0 = s * 4 + h * 2;  // logical 16B chunk of this k-half
            i32x8 af[4], bf[2];
#pragma unroll
            for (int si = 0; si < 4; si++) {
                const unsigned char* base = cA + (wr * 128 + si * 32 + m) * 128;
                i32x4 lo = *(const i32x4*)(base + ((c0 ^ e2) << 4));
                i32x4 hi = *(const i32x4*)(base + (((c0 + 1) ^ e2) << 4));
                af[si] = __builtin_shufflevector(lo, hi, 0, 1, 2, 3, 4, 5, 6, 7);
            }
#pragma unroll
            for (int sj = 0; sj < 2; sj++) {
                const unsigned char* base = cB + (wc * 64 + sj * 32 + m) * 128;
                i32x4 lo = *(const i32x4*)(base + ((c0 ^ e2) << 4));
                i32x4 hi = *(const i32x4*)(base + (((c0 + 1) ^ e2) << 4));
                bf[sj] = __builtin_shufflevector(lo, hi, 0, 1, 2, 3, 4, 5, 6, 7);
            }
            __builtin_amdgcn_s_barrier();  // raw: no vmcnt drain
            __builtin_amdgcn_s_setprio(1);
#pragma unroll
            for (int si = 0; si < 4; si++)
#pragma unroll
                for (int sj = 0; sj < 2; sj++)
                    acc[si][sj] = __builtin_amdgcn_mfma_scale_f32_32x32x64_f8f6f4(
                        af[si], bf[sj], acc[si][sj], 0 /*A fmt fp8*/,
                        0 /*B fmt fp8*/, 0, 127 /*scale A = 2^0*/,
                        0, 127 /*scale B = 2^0*/);
            __builtin_amdgcn_s_setprio(0);
            if (s == 0) __builtin_amdgcn_s_barrier();  // raw phase boundary
        }
        // Iter boundary: next buffer must be fully staged and this
        // buffer's reads done. __syncthreads drains vmcnt+lgkm and is a
        // full compiler fence (nothing leaks across iters).
        __syncthreads();
        cur ^= 1;
    }

    // Epilogue: ROW-side reduction (full G). C/D: col (within subtile) = m,
    // row within wave's 128 rows = si*32 + (reg&3) + 8*(reg>>2) + 4*h.
#pragma unroll
    for (int si = 0; si < 4; si++)
#pragma unroll
        for (int reg = 0; reg < 16; reg++) {
            const int row128 = si * 32 + (reg & 3) + 8 * (reg >> 2) + 4 * h;
            const int rIdx = wr * 128 + row128;  // row within block tile
            const int yr = sYr[rIdx];
            const float nr = sNr[rIdx];
            float dp = -1.0f, dn = BIGF;
#pragma unroll
            for (int sj = 0; sj < 2; sj++) {
                const int cIdx = wc * 64 + sj * 32 + m;
                float d2 = nr + sNc[cIdx] - 2.0f * acc[si][sj][reg];
                float d = sqrtf(fmaxf(d2, 0.0f));
                bool same = (yr == sYc[cIdx]);
                dp = fmaxf(dp, same ? d : -1.0f);
                dn = fminf(dn, same ? BIGF : d);
            }
            // Reduce over the 32 col-lanes (offsets 1..16 keep h fixed).
            for (int off = 1; off < 32; off <<= 1) {
                dp = fmaxf(dp, __shfl_xor(dp, off, 64));
                dn = fminf(dn, __shfl_xor(dn, off, 64));
            }
            if (m == 0) {  // lanes 0 (h=0) and 32 (h=1): disjoint rows
                redmax[wc][rIdx] = dp;
                redmin[wc][rIdx] = dn;
            }
        }
    __syncthreads();

    // Combine the 4 wc waves per row; one atomic pair per row.
    // Non-negative floats: uint cmp == float cmp; clamp max to 0 (true
    // dist_ap >= 0 via the diagonal self-pair).
    if (tid < 256) {
        float mx = fmaxf(fmaxf(redmax[0][tid], redmax[1][tid]),
                         fmaxf(redmax[2][tid], redmax[3][tid]));
        float mn = fminf(fminf(redmin[0][tid], redmin[1][tid]),
                         fminf(redmin[2][tid], redmin[3][tid]));
        atomicMax(&ap[rowBase + tid], __float_as_uint(fmaxf(mx, 0.0f)));
        atomicMin(&an[rowBase + tid], __float_as_uint(mn));
    }

    // Last block computes the loss (release fence before counter increment;
    // acquire fence + agent-scope atomic loads in the last block).
    __syncthreads();
    if (tid == 0) {
        __threadfence();
        s_done = atomicAdd(cnt, 1u);
    }
    __syncthreads();
    if (s_done == gridDim.x - 1) {
        __threadfence();
        float s = 0.0f;
        for (int i = tid; i < N; i += 512) {
            unsigned ua = __hip_atomic_load(&ap[i], __ATOMIC_RELAXED,
                                            __HIP_MEMORY_SCOPE_AGENT);
            unsigned ub = __hip_atomic_load(&an[i], __ATOMIC_RELAXED,
                                            __HIP_MEMORY_SCOPE_AGENT);
            s += fmaxf(__uint_as_float(ua) - __uint_as_float(ub) + MARGIN, 0.0f);
        }
        for (int off = 32; off > 0; off >>= 1) s += __shfl_xor(s, off, 64);
        if (lane == 0) lsum[wave] = s;
        __syncthreads();
        if (tid == 0) {
            float t = 0.0f;
#pragma unroll
            for (int w = 0; w < 8; w++) t += lsum[w];
            out[0] = t / (float)N;
        }
    }
}

extern "C" void kernel_launch(void* const* d_in, const int* in_sizes, int n_in,
                              void* d_out, int out_size, void* d_ws, size_t ws_size,
                              hipStream_t stream) {
    const float* X = (const float*)d_in[0];
    const int* Y = (const int*)d_in[1];
    float* out = (float*)d_out;
    const int N = in_sizes[1];          // 4096
    const int K = in_sizes[0] / N;      // 2048

    char* ws = (char*)d_ws;
    unsigned char* Xq = (unsigned char*)ws;                         // N*K bytes
    float* nrm = (float*)(ws + (size_t)N * K);
    unsigned* ap = (unsigned*)((char*)nrm + (size_t)N * 4);
    unsigned* an = (unsigned*)((char*)ap + (size_t)N * 4);
    unsigned* cnt = (unsigned*)((char*)an + (size_t)N * 4);

    convert_norm_kernel<<<N / 4, 256, 0, stream>>>(X, Xq, nrm, ap, an, cnt, K);
    const int NB = N / 256;
    gemm_reduce_kernel<<<NB * NB, 512, 0, stream>>>(Xq, nrm, Y, ap, an, cnt,
                                                    out, N, K);
}